// Round 1
// baseline (920.293 us; speedup 1.0000x reference)
//
#include <hip/hip_runtime.h>

// ---------------- workspace layout (float offsets) ----------------
constexpr size_t OFF_Y0   = 0;         // 8*16*128*128 = 2097152
constexpr size_t OFF_Y1   = 2097152;   // 8*32*64*64   = 1048576
constexpr size_t OFF_Y2   = 3145728;   // 8*64*32*32   = 524288
constexpr size_t OFF_Y3   = 3670016;   // 8*128*16*16  = 262144
constexpr size_t OFF_SS0  = 3932160;   // 8*16*2
constexpr size_t OFF_SS1  = 3932416;   // 8*32*2
constexpr size_t OFF_SS2  = 3932928;   // 8*64*2
constexpr size_t OFF_SS3  = 3933952;   // 8*128*2
constexpr size_t OFF_FEAT = 3936000;   // 8*128
constexpr size_t OFF_WGT  = 3937024;   // 8*20 (padded)
constexpr size_t OFF_T    = 3937280;   // 300*1089 = 326700
constexpr size_t OFF_LUT4 = 4264064;   // 8*35937*4 = 1149984  (16B aligned)
// total = 5414048 floats = ~21.7 MB

// ---------------- conv stride-2 3x3 + lrelu + instance-norm stats ----------------
// One block per (oc, b) plane. Input normalization (prev layer's instance norm,
// or the MEAN/STD image norm for the first layer) is folded into the weights:
//   contribution = (w*sc)*x + (w*sf)   for in-bounds taps, 0 for OOB taps.
// Interior outputs (oy>0 && ox0>0) have all taps in-bounds -> add precomputed
// shift-sum once. With stride 2 / pad 1 / even size, only top/left edges clip.
template<int CIN, int HIN, int WIN, int BLK, bool FIRST>
__global__ __launch_bounds__(BLK) void conv_s2_strip(
    const float* __restrict__ xin, const float* __restrict__ wgt,
    const float* __restrict__ bias, const float* __restrict__ ss_in,
    const float* __restrict__ gcur, const float* __restrict__ bcur,
    float* __restrict__ yout, float* __restrict__ ss_out)
{
  constexpr int HOUT = HIN/2, WOUT = WIN/2, NPX = HOUT*WOUT;
  constexpr int NSTRIP = NPX/4, SPW = WOUT/4;
  const int oc = blockIdx.x, b = blockIdx.y;
  const int COUT = gridDim.x;

  __shared__ float sw[CIN*9];
  __shared__ float sh[CIN*9];
  __shared__ float s_shsum;
  __shared__ float rbuf[2][BLK/64];

  if (threadIdx.x == 0) s_shsum = 0.f;
  for (int i = threadIdx.x; i < CIN*9; i += BLK) {
    int ic = i/9;
    float sc, sf;
    if constexpr (FIRST) {
      const float mv[3] = {0.485f, 0.456f, 0.406f};
      const float sv[3] = {0.229f, 0.224f, 0.225f};
      sc = 1.f/sv[ic]; sf = -mv[ic]/sv[ic];
    } else {
      sc = ss_in[(b*CIN+ic)*2+0]; sf = ss_in[(b*CIN+ic)*2+1];
    }
    float w = wgt[oc*CIN*9 + i];
    sw[i] = w*sc; sh[i] = w*sf;
  }
  __syncthreads();
  {
    float part = 0.f;
    for (int i = threadIdx.x; i < CIN*9; i += BLK) part += sh[i];
    #pragma unroll
    for (int off = 32; off; off >>= 1) part += __shfl_down(part, off);
    if ((threadIdx.x & 63) == 0) atomicAdd(&s_shsum, part);
  }
  __syncthreads();
  const float shsum = s_shsum;
  const float bb = bias[oc];
  const float* xb = xin + (size_t)b*CIN*HIN*WIN;
  float* yp = yout + ((size_t)b*COUT + oc)*NPX;
  float lsum = 0.f, lsq = 0.f;

  for (int s = threadIdx.x; s < NSTRIP; s += BLK) {
    int oy = s / SPW, sx = s - oy*SPW, ox0 = sx*4;
    float acc[4];
    if (oy > 0 && ox0 > 0) {
      #pragma unroll
      for (int j = 0; j < 4; ++j) acc[j] = bb + shsum;
      const float* x0 = xb + (oy*2-1)*WIN + (ox0*2-1);
      for (int ic = 0; ic < CIN; ++ic) {
        const float* xp = x0 + ic*HIN*WIN;
        const float* wp = &sw[ic*9];
        #pragma unroll
        for (int ky = 0; ky < 3; ++ky) {
          const float* row = xp + ky*WIN;
          float xv[9];
          #pragma unroll
          for (int t = 0; t < 9; ++t) xv[t] = row[t];
          float w0 = wp[ky*3], w1 = wp[ky*3+1], w2 = wp[ky*3+2];
          acc[0] += w0*xv[0] + w1*xv[1] + w2*xv[2];
          acc[1] += w0*xv[2] + w1*xv[3] + w2*xv[4];
          acc[2] += w0*xv[4] + w1*xv[5] + w2*xv[6];
          acc[3] += w0*xv[6] + w1*xv[7] + w2*xv[8];
        }
      }
    } else {
      #pragma unroll
      for (int j = 0; j < 4; ++j) acc[j] = bb;
      for (int ic = 0; ic < CIN; ++ic) {
        const float* xp = xb + ic*HIN*WIN;
        const float* wp = &sw[ic*9];
        const float* hp = &sh[ic*9];
        #pragma unroll
        for (int ky = 0; ky < 3; ++ky) {
          int iy = oy*2-1+ky;
          if (iy < 0) continue;
          const float* row = xp + iy*WIN;
          #pragma unroll
          for (int kx = 0; kx < 3; ++kx) {
            float w = wp[ky*3+kx], hh = hp[ky*3+kx];
            #pragma unroll
            for (int j = 0; j < 4; ++j) {
              int ix = (ox0+j)*2-1+kx;
              if (ix >= 0) acc[j] += w*row[ix] + hh;
            }
          }
        }
      }
    }
    float4 o;
    float* op = (float*)&o;
    #pragma unroll
    for (int j = 0; j < 4; ++j) {
      float a = acc[j];
      a = a >= 0.f ? a : 0.2f*a;       // lrelu
      op[j] = a;
      lsum += a; lsq += a*a;
    }
    *(float4*)(yp + oy*WOUT + ox0) = o;
  }

  // block-reduce stats -> per-(b,oc) scale/shift for the NEXT layer's load
  #pragma unroll
  for (int off = 32; off; off >>= 1) {
    lsum += __shfl_down(lsum, off);
    lsq  += __shfl_down(lsq,  off);
  }
  int wid = threadIdx.x >> 6;
  if ((threadIdx.x & 63) == 0) { rbuf[0][wid] = lsum; rbuf[1][wid] = lsq; }
  __syncthreads();
  if (threadIdx.x == 0) {
    float S = 0.f, Q = 0.f;
    #pragma unroll
    for (int w = 0; w < BLK/64; ++w) { S += rbuf[0][w]; Q += rbuf[1][w]; }
    float mean = S/(float)NPX;
    float var  = Q/(float)NPX - mean*mean;
    float rstd = rsqrtf(var + 1e-5f);
    float g = gcur[oc], be = bcur[oc];
    ss_out[(b*COUT+oc)*2+0] = g*rstd;
    ss_out[(b*COUT+oc)*2+1] = be - mean*g*rstd;
  }
}

// ---------------- last conv (128->128, 16x16 -> 8x8) + lrelu + global mean -> feat ----------------
__global__ __launch_bounds__(64) void conv_s2_last(
    const float* __restrict__ xin, const float* __restrict__ wgt,
    const float* __restrict__ bias, const float* __restrict__ ss_in,
    float* __restrict__ feat)
{
  constexpr int CIN = 128;
  const int oc = blockIdx.x, b = blockIdx.y;
  __shared__ float sw[CIN*9];
  __shared__ float sh[CIN*9];
  __shared__ float s_shsum;
  for (int i = threadIdx.x; i < CIN*9; i += 64) {
    int ic = i/9;
    float sc = ss_in[(b*CIN+ic)*2+0], sf = ss_in[(b*CIN+ic)*2+1];
    float w = wgt[oc*CIN*9 + i];
    sw[i] = w*sc; sh[i] = w*sf;
  }
  __syncthreads();
  float part = 0.f;
  for (int i = threadIdx.x; i < CIN*9; i += 64) part += sh[i];
  #pragma unroll
  for (int off = 32; off; off >>= 1) part += __shfl_down(part, off);
  if (threadIdx.x == 0) s_shsum = part;
  __syncthreads();

  const int p = threadIdx.x;       // 64 px = 8x8
  const int oy = p >> 3, ox = p & 7;
  const float* xb = xin + (size_t)b*CIN*256;
  float acc;
  if (oy > 0 && ox > 0) {
    acc = bias[oc] + s_shsum;
    const float* x0 = xb + (oy*2-1)*16 + (ox*2-1);
    for (int ic = 0; ic < CIN; ++ic) {
      const float* xp = x0 + ic*256;
      const float* wp = &sw[ic*9];
      #pragma unroll
      for (int ky = 0; ky < 3; ++ky) {
        const float* row = xp + ky*16;
        acc += wp[ky*3]*row[0] + wp[ky*3+1]*row[1] + wp[ky*3+2]*row[2];
      }
    }
  } else {
    acc = bias[oc];
    for (int ic = 0; ic < CIN; ++ic) {
      const float* xp = xb + ic*256;
      const float* wp = &sw[ic*9];
      const float* hp = &sh[ic*9];
      #pragma unroll
      for (int ky = 0; ky < 3; ++ky) {
        int iy = oy*2-1+ky;
        if (iy < 0) continue;
        #pragma unroll
        for (int kx = 0; kx < 3; ++kx) {
          int ix = ox*2-1+kx;
          if (ix >= 0) acc += wp[ky*3+kx]*xb[ic*256 + iy*16 + ix] + hp[ky*3+kx];
        }
      }
    }
  }
  acc = acc >= 0.f ? acc : 0.2f*acc;
  float s = acc;
  #pragma unroll
  for (int off = 32; off; off >>= 1) s += __shfl_down(s, off);
  if (threadIdx.x == 0) feat[b*128 + oc] = s * (1.0f/64.0f);
}

// ---------------- classifier head: h = hardswish(feat@W0^T+b0); weight = h@W1^T+b1 ----------------
__global__ __launch_bounds__(256) void head_kernel(
    const float* __restrict__ feat, const float* __restrict__ w0, const float* __restrict__ b0,
    const float* __restrict__ w1, const float* __restrict__ b1, float* __restrict__ wout)
{
  __shared__ float sh_h[8*128];
  const int tid = threadIdx.x;
  for (int i = tid; i < 8*128; i += 256) {
    int b = i >> 7, t = i & 127;
    const float* f = feat + b*128;
    const float* w = w0 + t*128;
    float a = b0[t];
    for (int k = 0; k < 128; ++k) a += f[k]*w[k];
    float c = fminf(fmaxf(a + 3.f, 0.f), 6.f);
    sh_h[i] = a * c * (1.f/6.f);            // hardswish
  }
  __syncthreads();
  for (int i = tid; i < 8*20; i += 256) {
    int b = i/20, n = i - b*20;
    const float* h = sh_h + b*128;
    const float* w = w1 + n*128;
    float a = b1[n];
    for (int k = 0; k < 128; ++k) a += h[k]*w[k];
    wout[b*20 + n] = a;
  }
}

// ---------------- T = luts(300x20) @ w_layers(20x1089) ----------------
__global__ __launch_bounds__(256) void tmat_kernel(
    const float* __restrict__ luts, const float* __restrict__ wl, float* __restrict__ T)
{
  int q = blockIdx.x*256 + threadIdx.x;
  int row = blockIdx.y;
  if (q >= 1089) return;
  float a = 0.f;
  #pragma unroll
  for (int w = 0; w < 20; ++w) a += luts[row*20 + w] * wl[w*1089 + q];
  T[row*1089 + q] = a;
}

// ---------------- per-batch 3D LUT, channel-interleaved float4 [bt][b][g][r] ----------------
// d3lut[bt,ch,bi,gi,ri] = sum_n weight[bt,n] * sum_s s_layers[d0,s] * T[(s*60+n*3+ch)*1089+q]
//   ch0: d0=ri, q=bi*33+gi | ch1: d0=gi, q=bi*33+ri | ch2: d0=bi, q=gi*33+ri
__global__ __launch_bounds__(256) void lut_kernel(
    const float* __restrict__ T, const float* __restrict__ wgt,
    const float* __restrict__ slay, float4* __restrict__ lut)
{
  int i = blockIdx.x*256 + threadIdx.x;
  int bt = blockIdx.y;
  if (i >= 35937) return;
  int bi = i / 1089, rem = i - bi*1089, gi = rem / 33, ri = rem - gi*33;
  float w[20];
  #pragma unroll
  for (int n = 0; n < 20; ++n) w[n] = wgt[bt*20 + n];
  const int qv[3] = { bi*33 + gi, bi*33 + ri, gi*33 + ri };
  const int d0v[3] = { ri, gi, bi };
  float outv[3];
  #pragma unroll
  for (int ch = 0; ch < 3; ++ch) {
    float val = 0.f;
    #pragma unroll
    for (int s = 0; s < 5; ++s) {
      float t = 0.f;
      #pragma unroll
      for (int n = 0; n < 20; ++n)
        t += w[n] * T[(s*60 + n*3 + ch)*1089 + qv[ch]];
      val += slay[d0v[ch]*5 + s] * t;
    }
    outv[ch] = val;
  }
  lut[(size_t)bt*35937 + i] = make_float4(outv[0], outv[1], outv[2], 0.f);
}

// ---------------- trilinear apply + residual ----------------
__global__ __launch_bounds__(256) void trilin_kernel(
    const float* __restrict__ img, const float4* __restrict__ lut, float* __restrict__ out)
{
  constexpr int NPX = 720*1280, NV = NPX/4;
  int v = blockIdx.x*256 + threadIdx.x;
  int bt = blockIdx.y;
  if (v >= NV) return;
  const float* ib = img + (size_t)bt*3*NPX;
  float4 r4 = *((const float4*)ib + v);
  float4 g4 = *((const float4*)(ib + NPX) + v);
  float4 b4 = *((const float4*)(ib + 2*NPX) + v);
  const float4* L = lut + (size_t)bt*35937;
  const float invbin = 32.0f/1.000001f;
  float4 ro, go, bo;
  float* rp = (float*)&ro; float* gp = (float*)&go; float* bp = (float*)&bo;
  #pragma unroll
  for (int j = 0; j < 4; ++j) {
    float r = ((float*)&r4)[j], g = ((float*)&g4)[j], b = ((float*)&b4)[j];
    float pr = r*invbin, pg = g*invbin, pb = b*invbin;
    int ri = (int)pr; ri = ri > 31 ? 31 : ri; ri = ri < 0 ? 0 : ri;
    int gi = (int)pg; gi = gi > 31 ? 31 : gi; gi = gi < 0 ? 0 : gi;
    int bi = (int)pb; bi = bi > 31 ? 31 : bi; bi = bi < 0 ? 0 : bi;
    float fr = pr - ri, fg = pg - gi, fb = pb - bi;
    int base = (bi*33 + gi)*33 + ri;
    float4 c000 = L[base],      c001 = L[base+1];
    float4 c010 = L[base+33],   c011 = L[base+34];
    float4 c100 = L[base+1089], c101 = L[base+1090];
    float4 c110 = L[base+1122], c111 = L[base+1123];
    float u1 = fr, u0 = 1.f-fr, v1 = fg, v0 = 1.f-fg, w1 = fb, w0 = 1.f-fb;
    float s000 = u0*v0*w0, s100 = u1*v0*w0, s010 = u0*v1*w0, s110 = u1*v1*w0;
    float s001 = u0*v0*w1, s101 = u1*v0*w1, s011 = u0*v1*w1, s111 = u1*v1*w1;
    float rr = c000.x*s000 + c001.x*s100 + c010.x*s010 + c011.x*s110
             + c100.x*s001 + c101.x*s101 + c110.x*s011 + c111.x*s111;
    float gg = c000.y*s000 + c001.y*s100 + c010.y*s010 + c011.y*s110
             + c100.y*s001 + c101.y*s101 + c110.y*s011 + c111.y*s111;
    float bb = c000.z*s000 + c001.z*s100 + c010.z*s010 + c011.z*s110
             + c100.z*s001 + c101.z*s101 + c110.z*s011 + c111.z*s111;
    rp[j] = rr + r; gp[j] = gg + g; bp[j] = bb + b;
  }
  float* ob = out + (size_t)bt*3*NPX;
  *((float4*)ob + v) = ro;
  *((float4*)(ob + NPX) + v) = go;
  *((float4*)(ob + 2*NPX) + v) = bo;
}

// ---------------- launcher ----------------
extern "C" void kernel_launch(void* const* d_in, const int* in_sizes, int n_in,
                              void* d_out, int out_size, void* d_ws, size_t ws_size,
                              hipStream_t stream) {
  const float* img     = (const float*)d_in[0];
  const float* img_org = (const float*)d_in[1];
  const float* c0w = (const float*)d_in[2];  const float* c0b = (const float*)d_in[3];
  const float* c1w = (const float*)d_in[4];  const float* c1b = (const float*)d_in[5];
  const float* c2w = (const float*)d_in[6];  const float* c2b = (const float*)d_in[7];
  const float* c3w = (const float*)d_in[8];  const float* c3b = (const float*)d_in[9];
  const float* c4w = (const float*)d_in[10]; const float* c4b = (const float*)d_in[11];
  const float* n0g = (const float*)d_in[12]; const float* n0b = (const float*)d_in[13];
  const float* n1g = (const float*)d_in[14]; const float* n1b = (const float*)d_in[15];
  const float* n2g = (const float*)d_in[16]; const float* n2b = (const float*)d_in[17];
  const float* n3g = (const float*)d_in[18]; const float* n3b = (const float*)d_in[19];
  const float* cls0_w = (const float*)d_in[20]; const float* cls0_b = (const float*)d_in[21];
  const float* cls1_w = (const float*)d_in[22]; const float* cls1_b = (const float*)d_in[23];
  const float* s_layers = (const float*)d_in[24];
  const float* w_layers = (const float*)d_in[25];
  const float* luts     = (const float*)d_in[26];
  float* ws = (float*)d_ws;
  float* out = (float*)d_out;

  conv_s2_strip<3, 256, 256, 1024, true><<<dim3(16, 8), 1024, 0, stream>>>(
      img, c0w, c0b, nullptr, n0g, n0b, ws + OFF_Y0, ws + OFF_SS0);
  conv_s2_strip<16, 128, 128, 512, false><<<dim3(32, 8), 512, 0, stream>>>(
      ws + OFF_Y0, c1w, c1b, ws + OFF_SS0, n1g, n1b, ws + OFF_Y1, ws + OFF_SS1);
  conv_s2_strip<32, 64, 64, 256, false><<<dim3(64, 8), 256, 0, stream>>>(
      ws + OFF_Y1, c2w, c2b, ws + OFF_SS1, n2g, n2b, ws + OFF_Y2, ws + OFF_SS2);
  conv_s2_strip<64, 32, 32, 64, false><<<dim3(128, 8), 64, 0, stream>>>(
      ws + OFF_Y2, c3w, c3b, ws + OFF_SS2, n3g, n3b, ws + OFF_Y3, ws + OFF_SS3);
  conv_s2_last<<<dim3(128, 8), 64, 0, stream>>>(
      ws + OFF_Y3, c4w, c4b, ws + OFF_SS3, ws + OFF_FEAT);
  head_kernel<<<1, 256, 0, stream>>>(
      ws + OFF_FEAT, cls0_w, cls0_b, cls1_w, cls1_b, ws + OFF_WGT);
  tmat_kernel<<<dim3(5, 300), 256, 0, stream>>>(luts, w_layers, ws + OFF_T);
  lut_kernel<<<dim3(141, 8), 256, 0, stream>>>(
      ws + OFF_T, ws + OFF_WGT, s_layers, (float4*)(ws + OFF_LUT4));
  trilin_kernel<<<dim3(900, 8), 256, 0, stream>>>(
      img_org, (const float4*)(ws + OFF_LUT4), out);
}